// Round 1
// baseline (3596.359 us; speedup 1.0000x reference)
//
#include <hip/hip_runtime.h>
#include <cstdint>
#include <cstddef>

typedef __bf16 bf16;
typedef bf16 bf16x8 __attribute__((ext_vector_type(8)));
typedef float f32x4 __attribute__((ext_vector_type(4)));

#define GAS __attribute__((address_space(1)))
#define LAS __attribute__((address_space(3)))

__device__ __forceinline__ void async_cp16(const bf16* g, bf16* l) {
  __builtin_amdgcn_global_load_lds((const GAS unsigned int*)g,
                                   (LAS unsigned int*)l, 16, 0, 0);
}

__device__ __forceinline__ float gelu_f(float x) {
  return 0.5f * x * (1.0f + erff(x * 0.70710678118654752440f));
}

// ---------------- weight conversion ----------------
__global__ void __launch_bounds__(256) f2b_kernel(const float* __restrict__ in,
                                                  bf16* __restrict__ out, int n) {
  int i = (blockIdx.x * 256 + threadIdx.x) * 4;
  if (i >= n) return;
  float4 v = *(const float4*)&in[i];
  union { uint2 u; bf16 e[4]; } o;
  o.e[0] = (bf16)v.x; o.e[1] = (bf16)v.y; o.e[2] = (bf16)v.z; o.e[3] = (bf16)v.w;
  *(uint2*)&out[i] = o.u;
}

// 3-way hi/mid/lo split for the precision-critical router GEMM
__global__ void __launch_bounds__(256) split3_kernel(const float* __restrict__ in,
    bf16* __restrict__ oh, bf16* __restrict__ om, bf16* __restrict__ ol, int n) {
  int i = (blockIdx.x * 256 + threadIdx.x) * 4;
  if (i >= n) return;
  float4 v = *(const float4*)&in[i];
  float a[4] = {v.x, v.y, v.z, v.w};
  union { uint2 u; bf16 e[4]; } h, m, l;
#pragma unroll
  for (int j = 0; j < 4; j++) {
    h.e[j] = (bf16)a[j];
    float r = a[j] - (float)h.e[j];
    m.e[j] = (bf16)r;
    l.e[j] = (bf16)(r - (float)m.e[j]);
  }
  *(uint2*)&oh[i] = h.u;
  *(uint2*)&om[i] = m.u;
  *(uint2*)&ol[i] = l.u;
}

// ---------------- layernorm (fp32 in, bf16 out; optional 3-way split) ----------------
template<int SPLIT>
__global__ void __launch_bounds__(256) ln_kernel(const float* __restrict__ X,
    const float* __restrict__ w, const float* __restrict__ b,
    bf16* __restrict__ oh, bf16* __restrict__ om, bf16* __restrict__ ol) {
  const int row = blockIdx.x;
  const int tid = threadIdx.x;
  const float4 xv = *(const float4*)&X[(size_t)row * 1024 + tid * 4];
  float s1 = xv.x + xv.y + xv.z + xv.w;
  float s2 = xv.x * xv.x + xv.y * xv.y + xv.z * xv.z + xv.w * xv.w;
#pragma unroll
  for (int d = 1; d < 64; d <<= 1) {
    s1 += __shfl_xor(s1, d, 64);
    s2 += __shfl_xor(s2, d, 64);
  }
  __shared__ float red[8];
  if ((tid & 63) == 0) { red[tid >> 6] = s1; red[4 + (tid >> 6)] = s2; }
  __syncthreads();
  s1 = red[0] + red[1] + red[2] + red[3];
  s2 = red[4] + red[5] + red[6] + red[7];
  const float mu = s1 * (1.0f / 1024.0f);
  const float var = s2 * (1.0f / 1024.0f) - mu * mu;
  const float rs = rsqrtf(var + 1e-5f);
  const float4 wv = *(const float4*)&w[tid * 4];
  const float4 bv = *(const float4*)&b[tid * 4];
  float y[4] = {(xv.x - mu) * rs * wv.x + bv.x,
                (xv.y - mu) * rs * wv.y + bv.y,
                (xv.z - mu) * rs * wv.z + bv.z,
                (xv.w - mu) * rs * wv.w + bv.w};
  union { uint2 u; bf16 e[4]; } h;
#pragma unroll
  for (int j = 0; j < 4; j++) h.e[j] = (bf16)y[j];
  *(uint2*)&oh[(size_t)row * 1024 + tid * 4] = h.u;
  if (SPLIT == 3) {
    union { uint2 u; bf16 e[4]; } m, l;
#pragma unroll
    for (int j = 0; j < 4; j++) {
      float r = y[j] - (float)h.e[j];
      m.e[j] = (bf16)r;
      l.e[j] = (bf16)(r - (float)m.e[j]);
    }
    *(uint2*)&om[(size_t)row * 1024 + tid * 4] = m.u;
    *(uint2*)&ol[(size_t)row * 1024 + tid * 4] = l.u;
  }
}

// ---------------- m97-style NT GEMM: C[M,N] = A[M,K] * B[N,K]^T ----------------
// MODE 0: Cb  = bf16(acc + bias)                      (qkv proj)
// MODE 1: C32 = Res + acc + bias                      (attn out + residual)
// MODE 2: Cb  = bf16(gelu(acc + bias))                (ffn up)
// MODE 3: if (gate[row] >= level) C32 = Res + acc + b (ffn down, gated residual)
// MODE 4: C32 += acc                                  (router split pass)
// MODE 5: C32  = acc                                  (router first pass)
template<int MODE>
__global__ void __launch_bounds__(256) gemm_nt(
    const bf16* __restrict__ A, const bf16* __restrict__ B,
    const float* __restrict__ bias, const float* __restrict__ Res,
    float* __restrict__ C32, bf16* __restrict__ Cb,
    const int* __restrict__ gate, int M, int N, int K, int level) {
  __shared__ bf16 As[128 * 32];
  __shared__ bf16 Bs[128 * 32];
  const int tid = threadIdx.x;
  const int w = tid >> 6, lane = tid & 63;
  const int lr = lane & 15, lq = lane >> 4;
  const int m0 = blockIdx.y * 128, n0 = blockIdx.x * 128;
  const int wm = (w >> 1) * 64, wn = (w & 1) * 64;

  f32x4 acc[4][4] = {};

  const bf16* ga = A + (size_t)(m0 + (tid >> 2)) * K + (tid & 3) * 8;
  const bf16* gb = B + (size_t)(n0 + (tid >> 2)) * K + (tid & 3) * 8;
  bf16* la = As + w * 512;   // HW adds lane*16B; layout = row-major 128x32, no pad
  bf16* lb = Bs + w * 512;
  const size_t step64 = (size_t)64 * K;

  for (int k0 = 0; k0 < K; k0 += 32) {
    __syncthreads();
    async_cp16(ga + k0, la);
    async_cp16(ga + step64 + k0, la + 2048);
    async_cp16(gb + k0, lb);
    async_cp16(gb + step64 + k0, lb + 2048);
    __syncthreads();
    bf16x8 af[4], bfr[4];
#pragma unroll
    for (int i = 0; i < 4; i++)
      af[i] = *(const bf16x8*)&As[(wm + i * 16 + lr) * 32 + lq * 8];
#pragma unroll
    for (int i = 0; i < 4; i++)
      bfr[i] = *(const bf16x8*)&Bs[(wn + i * 16 + lr) * 32 + lq * 8];
#pragma unroll
    for (int mi = 0; mi < 4; mi++)
#pragma unroll
      for (int ni = 0; ni < 4; ni++)
        acc[mi][ni] = __builtin_amdgcn_mfma_f32_16x16x32_bf16(
            af[mi], bfr[ni], acc[mi][ni], 0, 0, 0);
  }

#pragma unroll
  for (int mi = 0; mi < 4; mi++) {
    const int rbase = m0 + wm + mi * 16 + lq * 4;
#pragma unroll
    for (int ni = 0; ni < 4; ni++) {
      const int c = n0 + wn + ni * 16 + lr;
      float bv = 0.0f;
      if (MODE <= 3) bv = bias[c];
#pragma unroll
      for (int r = 0; r < 4; r++) {
        const size_t row = (size_t)(rbase + r);
        const float v = acc[mi][ni][r];
        if (MODE == 0) {
          Cb[row * N + c] = (bf16)(v + bv);
        } else if (MODE == 1) {
          C32[row * N + c] = Res[row * N + c] + v + bv;
        } else if (MODE == 2) {
          Cb[row * N + c] = (bf16)gelu_f(v + bv);
        } else if (MODE == 3) {
          if (gate[row] >= level) C32[row * N + c] = Res[row * N + c] + v + bv;
        } else if (MODE == 4) {
          C32[row * N + c] += v;
        } else {
          C32[row * N + c] = v;
        }
      }
    }
  }
}

// ---------------- router tail: fp32 gelu(+bias), logits + argmax ----------------
__global__ void __launch_bounds__(256) gelu_bias_kernel(float* __restrict__ t,
    const float* __restrict__ bias, int n) {
  int i = (blockIdx.x * 256 + threadIdx.x) * 4;
  if (i >= n) return;
  float4 v = *(const float4*)&t[i];
  float4 bb = *(const float4*)&bias[i & 1023];
  v.x = gelu_f(v.x + bb.x);
  v.y = gelu_f(v.y + bb.y);
  v.z = gelu_f(v.z + bb.z);
  v.w = gelu_f(v.w + bb.w);
  *(float4*)&t[i] = v;
}

__global__ void __launch_bounds__(256) router_logits(const float* __restrict__ h,
    const float* __restrict__ w2, const float* __restrict__ b2,
    float* __restrict__ logits_out, float* __restrict__ depths_out,
    int* __restrict__ gate) {
  const int row = blockIdx.x * 4 + (threadIdx.x >> 6);
  const int lane = threadIdx.x & 63;
  const float* hr = h + (size_t)row * 1024;
  float part[6] = {0, 0, 0, 0, 0, 0};
  for (int kc = lane; kc < 256; kc += 64) {
    float4 hv = *(const float4*)&hr[kc * 4];
#pragma unroll
    for (int j = 0; j < 6; j++) {
      float4 wv = *(const float4*)&w2[j * 1024 + kc * 4];
      part[j] += hv.x * wv.x + hv.y * wv.y + hv.z * wv.z + hv.w * wv.w;
    }
  }
#pragma unroll
  for (int j = 0; j < 6; j++)
#pragma unroll
    for (int d = 1; d < 64; d <<= 1) part[j] += __shfl_xor(part[j], d, 64);
  if (lane == 0) {
    float best = -1e30f;
    int bi = 0;
#pragma unroll
    for (int j = 0; j < 6; j++) {
      const float v = part[j] + b2[j];
      logits_out[(size_t)row * 6 + j] = v;
      if (v > best) { best = v; bi = j; }   // strict > keeps first max (jnp.argmax)
    }
    depths_out[row] = (float)(bi + 1);
    gate[row] = bi + 1;
  }
}

// ---------------- flash attention: one WG per (b, h, 64-row q-tile) ----------------
__global__ void __launch_bounds__(256) attn_kernel(const bf16* __restrict__ qkv,
                                                   bf16* __restrict__ ctx) {
  __shared__ bf16 Qs[64 * 72];   // +8 pad breaks 16-way b128 conflicts
  __shared__ bf16 Ks[64 * 72];
  __shared__ bf16 Vt[64 * 72];   // V transposed: [hd][token]
  __shared__ bf16 Ps[64 * 72];   // P in A-operand layout, wave-private rows
  const int tid = threadIdx.x;
  const int w = tid >> 6, lane = tid & 63;
  const int lr = lane & 15, lq = lane >> 4;
  const int qt = blockIdx.x & 15;
  const int bh = blockIdx.x >> 4;
  const int b = bh >> 4, h = bh & 15;
  const size_t rowbase = (size_t)b * 1024;
  const int hcol = h * 64;

  // stage Q (64x64)
#pragma unroll
  for (int i = 0; i < 2; i++) {
    const int c = tid + i * 256;
    const int r = c >> 3, k8 = (c & 7) * 8;
    uint4 v = *(const uint4*)&qkv[(rowbase + qt * 64 + r) * 3072 + hcol + k8];
    *(uint4*)&Qs[r * 72 + k8] = v;
  }

  float m_old[4], l_run[4];
  f32x4 o[4];
#pragma unroll
  for (int r = 0; r < 4; r++) { m_old[r] = -1e30f; l_run[r] = 0.0f; }
#pragma unroll
  for (int i = 0; i < 4; i++) o[i] = (f32x4)0.0f;

  for (int kb = 0; kb < 16; kb++) {
    __syncthreads();
#pragma unroll
    for (int i = 0; i < 2; i++) {
      const int c = tid + i * 256;
      const int r = c >> 3, k8 = (c & 7) * 8;
      uint4 v = *(const uint4*)&qkv[(rowbase + kb * 64 + r) * 3072 + 1024 + hcol + k8];
      *(uint4*)&Ks[r * 72 + k8] = v;
    }
#pragma unroll
    for (int i = 0; i < 2; i++) {
      const int c = tid + i * 256;
      const int tok = c >> 3, hd0 = (c & 7) * 8;
      uint4 v = *(const uint4*)&qkv[(rowbase + kb * 64 + tok) * 3072 + 2048 + hcol + hd0];
      union { uint4 u; bf16 e[8]; } tv;
      tv.u = v;
#pragma unroll
      for (int j = 0; j < 8; j++) Vt[(hd0 + j) * 72 + tok] = tv.e[j];
    }
    __syncthreads();

    // S = Q K^T / sqrt(64): wave w owns q rows [w*16, w*16+16)
    f32x4 s[4];
#pragma unroll
    for (int kf = 0; kf < 4; kf++) {
      f32x4 sa = (f32x4)0.0f;
#pragma unroll
      for (int hs = 0; hs < 2; hs++) {
        bf16x8 aq = *(const bf16x8*)&Qs[(w * 16 + lr) * 72 + hs * 32 + lq * 8];
        bf16x8 bk = *(const bf16x8*)&Ks[(kf * 16 + lr) * 72 + hs * 32 + lq * 8];
        sa = __builtin_amdgcn_mfma_f32_16x16x32_bf16(aq, bk, sa, 0, 0, 0);
      }
      s[kf] = sa * 0.125f;
    }

    // online softmax; C-layout row = lq*4 + r
#pragma unroll
    for (int r = 0; r < 4; r++) {
      float mx = fmaxf(fmaxf(s[0][r], s[1][r]), fmaxf(s[2][r], s[3][r]));
#pragma unroll
      for (int d = 1; d < 16; d <<= 1) mx = fmaxf(mx, __shfl_xor(mx, d, 64));
      const float mn = fmaxf(m_old[r], mx);
      const float alpha = __expf(m_old[r] - mn);
      float psum = 0.0f;
#pragma unroll
      for (int kf = 0; kf < 4; kf++) {
        const float p = __expf(s[kf][r] - mn);
        s[kf][r] = p;
        psum += p;
      }
#pragma unroll
      for (int d = 1; d < 16; d <<= 1) psum += __shfl_xor(psum, d, 64);
      l_run[r] = l_run[r] * alpha + psum;
      m_old[r] = mn;
#pragma unroll
      for (int hf = 0; hf < 4; hf++) o[hf][r] *= alpha;
    }

    // P: C-layout -> A-layout via LDS (wave-private rows, no barrier needed)
#pragma unroll
    for (int kf = 0; kf < 4; kf++)
#pragma unroll
      for (int r = 0; r < 4; r++)
        Ps[(w * 16 + lq * 4 + r) * 72 + kf * 16 + lr] = (bf16)s[kf][r];

    // O += P * V
#pragma unroll
    for (int hf = 0; hf < 4; hf++) {
#pragma unroll
      for (int ks = 0; ks < 2; ks++) {
        bf16x8 ap = *(const bf16x8*)&Ps[(w * 16 + lr) * 72 + ks * 32 + lq * 8];
        bf16x8 bv = *(const bf16x8*)&Vt[(hf * 16 + lr) * 72 + ks * 32 + lq * 8];
        o[hf] = __builtin_amdgcn_mfma_f32_16x16x32_bf16(ap, bv, o[hf], 0, 0, 0);
      }
    }
  }

#pragma unroll
  for (int r = 0; r < 4; r++) {
    const float inv = 1.0f / l_run[r];
    const size_t row = rowbase + qt * 64 + w * 16 + lq * 4 + r;
#pragma unroll
    for (int hf = 0; hf < 4; hf++)
      ctx[row * 1024 + hcol + hf * 16 + lr] = (bf16)(o[hf][r] * inv);
  }
}

// ---------------- launch ----------------
extern "C" void kernel_launch(void* const* d_in, const int* in_sizes, int n_in,
                              void* d_out, int out_size, void* d_ws, size_t ws_size,
                              hipStream_t stream) {
  (void)in_sizes; (void)n_in; (void)out_size; (void)ws_size;
  const float* x    = (const float*)d_in[0];
  const float* a_nw = (const float*)d_in[1];
  const float* a_nb = (const float*)d_in[2];
  const float* in_w = (const float*)d_in[3];
  const float* in_b = (const float*)d_in[4];
  const float* o_w  = (const float*)d_in[5];
  const float* o_b  = (const float*)d_in[6];
  const float* f_nw = (const float*)d_in[7];
  const float* f_nb = (const float*)d_in[8];
  const float* w1   = (const float*)d_in[9];
  const float* b1   = (const float*)d_in[10];
  const float* w2   = (const float*)d_in[11];
  const float* b2   = (const float*)d_in[12];
  const float* r_nw = (const float*)d_in[13];
  const float* r_nb = (const float*)d_in[14];
  const float* rw1  = (const float*)d_in[15];
  const float* rb1  = (const float*)d_in[16];
  const float* rw2  = (const float*)d_in[17];
  const float* rb2  = (const float*)d_in[18];

  float* cur    = (float*)d_out;          // (8,1024,1024) fp32 lives in d_out
  float* depths = cur + 8388608;          // (8,1024) as float
  float* logits = depths + 8192;          // (8,1024,6) fp32

  char* ws = (char*)d_ws;
  bf16* wb_in  = (bf16*)(ws + 0);          // 3072x1024
  bf16* wb_out = (bf16*)(ws + 6291456);    // 1024x1024
  bf16* wb_f1  = (bf16*)(ws + 8388608);    // 4096x1024
  bf16* wb_f2  = (bf16*)(ws + 16777216);   // 1024x4096
  bf16* r1h    = (bf16*)(ws + 25165824);   // rt_w1 hi
  bf16* r1m    = (bf16*)(ws + 27262976);   // rt_w1 mid
  bf16* r1l    = (bf16*)(ws + 29360128);   // rt_w1 lo
  bf16* Abuf   = (bf16*)(ws + 31457280);   // 8192x1024 bf16 (LN out / hi)
  bf16* Bbuf   = (bf16*)(ws + 48234496);   // 8192x1024 bf16 (LN mid / ctx)
  bf16* Big    = (bf16*)(ws + 65011712);   // 8192x4096 bf16 (qkv / ffn-h / LN lo)
  float* Tmp   = (float*)(ws + 132120576); // 8192x1024 fp32 (router h / attn residual)
  int*  gate   = (int*)(ws + 165675008);   // 8192 depths

  hipMemcpyAsync(cur, x, (size_t)8388608 * 4, hipMemcpyDeviceToDevice, stream);

  f2b_kernel<<<3072, 256, 0, stream>>>(in_w, wb_in, 3145728);
  f2b_kernel<<<1024, 256, 0, stream>>>(o_w, wb_out, 1048576);
  f2b_kernel<<<4096, 256, 0, stream>>>(w1, wb_f1, 4194304);
  f2b_kernel<<<4096, 256, 0, stream>>>(w2, wb_f2, 4194304);
  split3_kernel<<<1024, 256, 0, stream>>>(rw1, r1h, r1m, r1l, 1048576);

  // ---- router: 6-pass split-bf16 GEMM for fp32-accurate logits ----
  ln_kernel<3><<<8192, 256, 0, stream>>>(x, r_nw, r_nb, Abuf, Bbuf, Big);
  dim3 g1k(8, 64);
  gemm_nt<5><<<g1k, 256, 0, stream>>>(Abuf, r1h, nullptr, nullptr, Tmp, nullptr, nullptr, 8192, 1024, 1024, 0);
  gemm_nt<4><<<g1k, 256, 0, stream>>>(Abuf, r1m, nullptr, nullptr, Tmp, nullptr, nullptr, 8192, 1024, 1024, 0);
  gemm_nt<4><<<g1k, 256, 0, stream>>>(Bbuf, r1h, nullptr, nullptr, Tmp, nullptr, nullptr, 8192, 1024, 1024, 0);
  gemm_nt<4><<<g1k, 256, 0, stream>>>(Abuf, r1l, nullptr, nullptr, Tmp, nullptr, nullptr, 8192, 1024, 1024, 0);
  gemm_nt<4><<<g1k, 256, 0, stream>>>(Bbuf, r1m, nullptr, nullptr, Tmp, nullptr, nullptr, 8192, 1024, 1024, 0);
  gemm_nt<4><<<g1k, 256, 0, stream>>>(Big,  r1h, nullptr, nullptr, Tmp, nullptr, nullptr, 8192, 1024, 1024, 0);
  gelu_bias_kernel<<<8192, 256, 0, stream>>>(Tmp, rb1, 8388608);
  router_logits<<<2048, 256, 0, stream>>>(Tmp, rw2, rb2, logits, depths, gate);

  // ---- 6 recursion levels ----
  for (int level = 1; level <= 6; level++) {
    ln_kernel<1><<<8192, 256, 0, stream>>>(cur, a_nw, a_nb, Abuf, nullptr, nullptr);
    gemm_nt<0><<<dim3(24, 64), 256, 0, stream>>>(Abuf, wb_in, in_b, nullptr, nullptr, Big, nullptr, 8192, 3072, 1024, 0);
    attn_kernel<<<2048, 256, 0, stream>>>(Big, Bbuf);
    gemm_nt<1><<<dim3(8, 64), 256, 0, stream>>>(Bbuf, wb_out, o_b, cur, Tmp, nullptr, nullptr, 8192, 1024, 1024, 0);
    ln_kernel<1><<<8192, 256, 0, stream>>>(Tmp, f_nw, f_nb, Abuf, nullptr, nullptr);
    gemm_nt<2><<<dim3(32, 64), 256, 0, stream>>>(Abuf, wb_f1, b1, nullptr, nullptr, Big, nullptr, 8192, 4096, 1024, 0);
    gemm_nt<3><<<dim3(8, 64), 256, 0, stream>>>(Big, wb_f2, b2, Tmp, cur, nullptr, gate, 8192, 1024, 4096, level);
  }
}

// Round 2
// 3016.047 us; speedup vs baseline: 1.1924x; 1.1924x over previous
//
#include <hip/hip_runtime.h>
#include <cstdint>
#include <cstddef>

typedef __bf16 bf16;
typedef bf16 bf16x8 __attribute__((ext_vector_type(8)));
typedef float f32x4 __attribute__((ext_vector_type(4)));

#define GAS __attribute__((address_space(1)))
#define LAS __attribute__((address_space(3)))

__device__ __forceinline__ void async_cp16(const bf16* g, bf16* l) {
  __builtin_amdgcn_global_load_lds((const GAS unsigned int*)g,
                                   (LAS unsigned int*)l, 16, 0, 0);
}

__device__ __forceinline__ float gelu_f(float x) {
  return 0.5f * x * (1.0f + erff(x * 0.70710678118654752440f));
}

// ---------------- weight conversion ----------------
__global__ void __launch_bounds__(256) f2b_kernel(const float* __restrict__ in,
                                                  bf16* __restrict__ out, int n) {
  int i = (blockIdx.x * 256 + threadIdx.x) * 4;
  if (i >= n) return;
  float4 v = *(const float4*)&in[i];
  union { uint2 u; bf16 e[4]; } o;
  o.e[0] = (bf16)v.x; o.e[1] = (bf16)v.y; o.e[2] = (bf16)v.z; o.e[3] = (bf16)v.w;
  *(uint2*)&out[i] = o.u;
}

// 3-way hi/mid/lo split for the precision-critical router GEMM
__global__ void __launch_bounds__(256) split3_kernel(const float* __restrict__ in,
    bf16* __restrict__ oh, bf16* __restrict__ om, bf16* __restrict__ ol, int n) {
  int i = (blockIdx.x * 256 + threadIdx.x) * 4;
  if (i >= n) return;
  float4 v = *(const float4*)&in[i];
  float a[4] = {v.x, v.y, v.z, v.w};
  union { uint2 u; bf16 e[4]; } h, m, l;
#pragma unroll
  for (int j = 0; j < 4; j++) {
    h.e[j] = (bf16)a[j];
    float r = a[j] - (float)h.e[j];
    m.e[j] = (bf16)r;
    l.e[j] = (bf16)(r - (float)m.e[j]);
  }
  *(uint2*)&oh[i] = h.u;
  *(uint2*)&om[i] = m.u;
  *(uint2*)&ol[i] = l.u;
}

// ---------------- layernorm (fp32 in, bf16 out; optional 3-way split) ----------------
template<int SPLIT>
__global__ void __launch_bounds__(256) ln_kernel(const float* __restrict__ X,
    const float* __restrict__ w, const float* __restrict__ b,
    bf16* __restrict__ oh, bf16* __restrict__ om, bf16* __restrict__ ol) {
  const int row = blockIdx.x;
  const int tid = threadIdx.x;
  const float4 xv = *(const float4*)&X[(size_t)row * 1024 + tid * 4];
  float s1 = xv.x + xv.y + xv.z + xv.w;
  float s2 = xv.x * xv.x + xv.y * xv.y + xv.z * xv.z + xv.w * xv.w;
#pragma unroll
  for (int d = 1; d < 64; d <<= 1) {
    s1 += __shfl_xor(s1, d, 64);
    s2 += __shfl_xor(s2, d, 64);
  }
  __shared__ float red[8];
  if ((tid & 63) == 0) { red[tid >> 6] = s1; red[4 + (tid >> 6)] = s2; }
  __syncthreads();
  s1 = red[0] + red[1] + red[2] + red[3];
  s2 = red[4] + red[5] + red[6] + red[7];
  const float mu = s1 * (1.0f / 1024.0f);
  const float var = s2 * (1.0f / 1024.0f) - mu * mu;
  const float rs = rsqrtf(var + 1e-5f);
  const float4 wv = *(const float4*)&w[tid * 4];
  const float4 bv = *(const float4*)&b[tid * 4];
  float y[4] = {(xv.x - mu) * rs * wv.x + bv.x,
                (xv.y - mu) * rs * wv.y + bv.y,
                (xv.z - mu) * rs * wv.z + bv.z,
                (xv.w - mu) * rs * wv.w + bv.w};
  union { uint2 u; bf16 e[4]; } h;
#pragma unroll
  for (int j = 0; j < 4; j++) h.e[j] = (bf16)y[j];
  *(uint2*)&oh[(size_t)row * 1024 + tid * 4] = h.u;
  if (SPLIT == 3) {
    union { uint2 u; bf16 e[4]; } m, l;
#pragma unroll
    for (int j = 0; j < 4; j++) {
      float r = y[j] - (float)h.e[j];
      m.e[j] = (bf16)r;
      l.e[j] = (bf16)(r - (float)m.e[j]);
    }
    *(uint2*)&om[(size_t)row * 1024 + tid * 4] = m.u;
    *(uint2*)&ol[(size_t)row * 1024 + tid * 4] = l.u;
  }
}

// ---------------- m97-style NT GEMM: C[M,N] = A[M,K] * B[N,K]^T ----------------
template<int MODE>
__global__ void __launch_bounds__(256) gemm_nt(
    const bf16* __restrict__ A, const bf16* __restrict__ B,
    const float* __restrict__ bias, const float* __restrict__ Res,
    float* __restrict__ C32, bf16* __restrict__ Cb,
    const int* __restrict__ gate, int M, int N, int K, int level) {
  __shared__ bf16 As[128 * 32];
  __shared__ bf16 Bs[128 * 32];
  const int tid = threadIdx.x;
  const int w = tid >> 6, lane = tid & 63;
  const int lr = lane & 15, lq = lane >> 4;
  const int m0 = blockIdx.y * 128, n0 = blockIdx.x * 128;
  const int wm = (w >> 1) * 64, wn = (w & 1) * 64;

  f32x4 acc[4][4] = {};

  const bf16* ga = A + (size_t)(m0 + (tid >> 2)) * K + (tid & 3) * 8;
  const bf16* gb = B + (size_t)(n0 + (tid >> 2)) * K + (tid & 3) * 8;
  bf16* la = As + w * 512;
  bf16* lb = Bs + w * 512;
  const size_t step64 = (size_t)64 * K;

  for (int k0 = 0; k0 < K; k0 += 32) {
    __syncthreads();
    async_cp16(ga + k0, la);
    async_cp16(ga + step64 + k0, la + 2048);
    async_cp16(gb + k0, lb);
    async_cp16(gb + step64 + k0, lb + 2048);
    __syncthreads();
    bf16x8 af[4], bfr[4];
#pragma unroll
    for (int i = 0; i < 4; i++)
      af[i] = *(const bf16x8*)&As[(wm + i * 16 + lr) * 32 + lq * 8];
#pragma unroll
    for (int i = 0; i < 4; i++)
      bfr[i] = *(const bf16x8*)&Bs[(wn + i * 16 + lr) * 32 + lq * 8];
#pragma unroll
    for (int mi = 0; mi < 4; mi++)
#pragma unroll
      for (int ni = 0; ni < 4; ni++)
        acc[mi][ni] = __builtin_amdgcn_mfma_f32_16x16x32_bf16(
            af[mi], bfr[ni], acc[mi][ni], 0, 0, 0);
  }

#pragma unroll
  for (int mi = 0; mi < 4; mi++) {
    const int rbase = m0 + wm + mi * 16 + lq * 4;
#pragma unroll
    for (int ni = 0; ni < 4; ni++) {
      const int c = n0 + wn + ni * 16 + lr;
      float bv = 0.0f;
      if (MODE <= 3) bv = bias[c];
#pragma unroll
      for (int r = 0; r < 4; r++) {
        const size_t row = (size_t)(rbase + r);
        const float v = acc[mi][ni][r];
        if (MODE == 0) {
          Cb[row * N + c] = (bf16)(v + bv);
        } else if (MODE == 1) {
          C32[row * N + c] = Res[row * N + c] + v + bv;
        } else if (MODE == 2) {
          Cb[row * N + c] = (bf16)gelu_f(v + bv);
        } else if (MODE == 3) {
          if (gate[row] >= level) C32[row * N + c] = Res[row * N + c] + v + bv;
        } else if (MODE == 4) {
          C32[row * N + c] += v;
        } else {
          C32[row * N + c] = v;
        }
      }
    }
  }
}

// ---------------- router tail ----------------
__global__ void __launch_bounds__(256) gelu_bias_kernel(float* __restrict__ t,
    const float* __restrict__ bias, int n) {
  int i = (blockIdx.x * 256 + threadIdx.x) * 4;
  if (i >= n) return;
  float4 v = *(const float4*)&t[i];
  float4 bb = *(const float4*)&bias[i & 1023];
  v.x = gelu_f(v.x + bb.x);
  v.y = gelu_f(v.y + bb.y);
  v.z = gelu_f(v.z + bb.z);
  v.w = gelu_f(v.w + bb.w);
  *(float4*)&t[i] = v;
}

__global__ void __launch_bounds__(256) router_logits(const float* __restrict__ h,
    const float* __restrict__ w2, const float* __restrict__ b2,
    float* __restrict__ logits_out, float* __restrict__ depths_out,
    int* __restrict__ gate) {
  const int row = blockIdx.x * 4 + (threadIdx.x >> 6);
  const int lane = threadIdx.x & 63;
  const float* hr = h + (size_t)row * 1024;
  float part[6] = {0, 0, 0, 0, 0, 0};
  for (int kc = lane; kc < 256; kc += 64) {
    float4 hv = *(const float4*)&hr[kc * 4];
#pragma unroll
    for (int j = 0; j < 6; j++) {
      float4 wv = *(const float4*)&w2[j * 1024 + kc * 4];
      part[j] += hv.x * wv.x + hv.y * wv.y + hv.z * wv.z + hv.w * wv.w;
    }
  }
#pragma unroll
  for (int j = 0; j < 6; j++)
#pragma unroll
    for (int d = 1; d < 64; d <<= 1) part[j] += __shfl_xor(part[j], d, 64);
  if (lane == 0) {
    float best = -1e30f;
    int bi = 0;
#pragma unroll
    for (int j = 0; j < 6; j++) {
      const float v = part[j] + b2[j];
      logits_out[(size_t)row * 6 + j] = v;
      if (v > best) { best = v; bi = j; }
    }
    depths_out[row] = (float)(bi + 1);
    gate[row] = bi + 1;
  }
}

// ---------------- V transpose: qkv V-slice -> vt (b,h,hd,tok) ----------------
__global__ void __launch_bounds__(256) vtrans_kernel(const bf16* __restrict__ qkv,
                                                     bf16* __restrict__ vt) {
  __shared__ bf16 T[64 * 64];   // element (tok,hd) at tok*64 + (hd ^ ((tok&7)<<3))
  const int tid = threadIdx.x;
  const int tb = blockIdx.x & 15, bh = blockIdx.x >> 4;
  const int b = bh >> 4, h = bh & 15;
#pragma unroll
  for (int i = 0; i < 2; i++) {
    const int c = tid + i * 256;
    const int tok = c >> 3, hd8 = (c & 7) * 8;
    uint4 v = *(const uint4*)&qkv[((size_t)b * 1024 + tb * 64 + tok) * 3072 + 2048 + h * 64 + hd8];
    *(uint4*)&T[tok * 64 + (hd8 ^ ((tok & 7) << 3))] = v;
  }
  __syncthreads();
#pragma unroll
  for (int i = 0; i < 2; i++) {
    const int c = tid + i * 256;
    const int hd = c >> 3, t8 = (c & 7) * 8;
    union { uint4 u; bf16 e[8]; } o;
#pragma unroll
    for (int j = 0; j < 8; j++)
      o.e[j] = T[(t8 + j) * 64 + (hd ^ (j << 3))];
    *(uint4*)&vt[((size_t)bh * 64 + hd) * 1024 + tb * 64 + t8] = o.u;
  }
}

// ---------------- flash attention (no-max softmax, deferred reductions) ----------------
__global__ void __launch_bounds__(256) attn_kernel(const bf16* __restrict__ qkv,
                                                   const bf16* __restrict__ vtg,
                                                   bf16* __restrict__ ctx) {
  __shared__ bf16 Qs[64 * 72];
  __shared__ bf16 Ks[64 * 72];
  __shared__ bf16 Vt[64 * 72];   // (hd,tok): hd*72 + (tok ^ (hd&56))
  __shared__ bf16 Ps[64 * 72];   // (q,k):   q*72  + (k   ^ (((q>>2)&7)<<3))
  const int tid = threadIdx.x;
  const int w = tid >> 6, lane = tid & 63;
  const int lr = lane & 15, lq = lane >> 4;
  const int blk = blockIdx.x;
  const int bh = (blk & 7) | ((blk >> 7) << 3);   // cluster 16 q-tiles per XCD
  const int qt = (blk >> 3) & 15;
  const int b = bh >> 4, h = bh & 15;
  const size_t rowbase = (size_t)b * 1024;
  const int hcol = h * 64;
  const size_t vbase = (size_t)bh * 65536;

  // stage Q (loop-invariant)
#pragma unroll
  for (int i = 0; i < 2; i++) {
    const int c = tid + i * 256;
    const int r = c >> 3, k8 = (c & 7) * 8;
    uint4 v = *(const uint4*)&qkv[(rowbase + qt * 64 + r) * 3072 + hcol + k8];
    *(uint4*)&Qs[r * 72 + k8] = v;
  }
  __syncthreads();
  bf16x8 aq[2];
#pragma unroll
  for (int hs = 0; hs < 2; hs++)
    aq[hs] = *(const bf16x8*)&Qs[(w * 16 + lr) * 72 + hs * 32 + lq * 8];

  float lsum[4] = {0.0f, 0.0f, 0.0f, 0.0f};
  f32x4 o[4];
#pragma unroll
  for (int i = 0; i < 4; i++) o[i] = (f32x4)0.0f;

  const int Sw = ((w * 4 + lq) & 7) << 3;     // Ps write swizzle (const per lane)
  const int Sr = ((w * 4 + (lr >> 2)) & 7) << 3; // Ps read swizzle

  for (int kb = 0; kb < 16; kb++) {
    __syncthreads();
#pragma unroll
    for (int i = 0; i < 2; i++) {
      const int c = tid + i * 256;
      const int r = c >> 3, k8 = (c & 7) * 8;
      uint4 v = *(const uint4*)&qkv[(rowbase + kb * 64 + r) * 3072 + 1024 + hcol + k8];
      *(uint4*)&Ks[r * 72 + k8] = v;
    }
#pragma unroll
    for (int i = 0; i < 2; i++) {
      const int c = tid + i * 256;
      const int hd = c >> 3, t8 = (c & 7) * 8;
      uint4 v = *(const uint4*)&vtg[vbase + (size_t)hd * 1024 + kb * 64 + t8];
      *(uint4*)&Vt[hd * 72 + (t8 ^ (hd & 56))] = v;
    }
    __syncthreads();

    // S = Q K^T (scale folded into exp)
    f32x4 s[4];
#pragma unroll
    for (int kf = 0; kf < 4; kf++) {
      f32x4 sa = (f32x4)0.0f;
#pragma unroll
      for (int hs = 0; hs < 2; hs++) {
        bf16x8 bk = *(const bf16x8*)&Ks[(kf * 16 + lr) * 72 + hs * 32 + lq * 8];
        sa = __builtin_amdgcn_mfma_f32_16x16x32_bf16(aq[hs], bk, sa, 0, 0, 0);
      }
      s[kf] = sa;
    }

    // p = exp(s/8); local partial row-sums (cross-lane reduce deferred to end)
#pragma unroll
    for (int kf = 0; kf < 4; kf++) {
#pragma unroll
      for (int r = 0; r < 4; r++) {
        const float p = __expf(s[kf][r] * 0.125f);
        lsum[r] += p;
        const int row = w * 16 + lq * 4 + r;
        Ps[row * 72 + ((kf * 16 + lr) ^ Sw)] = (bf16)p;
      }
    }

    // O += P V  (P frags hoisted: depend only on ks)
    bf16x8 ap[2];
#pragma unroll
    for (int ks = 0; ks < 2; ks++)
      ap[ks] = *(const bf16x8*)&Ps[(w * 16 + lr) * 72 + ((ks * 32 + lq * 8) ^ Sr)];
#pragma unroll
    for (int hf = 0; hf < 4; hf++) {
      const int vrow = hf * 16 + lr;
#pragma unroll
      for (int ks = 0; ks < 2; ks++) {
        bf16x8 bv = *(const bf16x8*)&Vt[vrow * 72 + ((ks * 32 + lq * 8) ^ (vrow & 56))];
        o[hf] = __builtin_amdgcn_mfma_f32_16x16x32_bf16(ap[ks], bv, o[hf], 0, 0, 0);
      }
    }
  }

  // deferred row-sum reduction across the 16 lanes sharing lq
#pragma unroll
  for (int r = 0; r < 4; r++) {
#pragma unroll
    for (int d = 1; d < 16; d <<= 1) lsum[r] += __shfl_xor(lsum[r], d, 64);
  }

#pragma unroll
  for (int r = 0; r < 4; r++) {
    const float inv = 1.0f / lsum[r];
    const size_t row = rowbase + qt * 64 + w * 16 + lq * 4 + r;
#pragma unroll
    for (int hf = 0; hf < 4; hf++)
      ctx[row * 1024 + hcol + hf * 16 + lr] = (bf16)(o[hf][r] * inv);
  }
}

// ---------------- launch ----------------
extern "C" void kernel_launch(void* const* d_in, const int* in_sizes, int n_in,
                              void* d_out, int out_size, void* d_ws, size_t ws_size,
                              hipStream_t stream) {
  (void)in_sizes; (void)n_in; (void)out_size; (void)ws_size;
  const float* x    = (const float*)d_in[0];
  const float* a_nw = (const float*)d_in[1];
  const float* a_nb = (const float*)d_in[2];
  const float* in_w = (const float*)d_in[3];
  const float* in_b = (const float*)d_in[4];
  const float* o_w  = (const float*)d_in[5];
  const float* o_b  = (const float*)d_in[6];
  const float* f_nw = (const float*)d_in[7];
  const float* f_nb = (const float*)d_in[8];
  const float* w1   = (const float*)d_in[9];
  const float* b1   = (const float*)d_in[10];
  const float* w2   = (const float*)d_in[11];
  const float* b2   = (const float*)d_in[12];
  const float* r_nw = (const float*)d_in[13];
  const float* r_nb = (const float*)d_in[14];
  const float* rw1  = (const float*)d_in[15];
  const float* rb1  = (const float*)d_in[16];
  const float* rw2  = (const float*)d_in[17];
  const float* rb2  = (const float*)d_in[18];

  float* cur    = (float*)d_out;
  float* depths = cur + 8388608;
  float* logits = depths + 8192;

  char* ws = (char*)d_ws;
  bf16* wb_in  = (bf16*)(ws + 0);
  bf16* wb_out = (bf16*)(ws + 6291456);
  bf16* wb_f1  = (bf16*)(ws + 8388608);
  bf16* wb_f2  = (bf16*)(ws + 16777216);
  bf16* r1h    = (bf16*)(ws + 25165824);
  bf16* r1m    = (bf16*)(ws + 27262976);
  bf16* r1l    = (bf16*)(ws + 29360128);
  bf16* Abuf   = (bf16*)(ws + 31457280);
  bf16* Bbuf   = (bf16*)(ws + 48234496);
  bf16* Big    = (bf16*)(ws + 65011712);
  float* Tmp   = (float*)(ws + 132120576);  // fp32 8192x1024
  bf16* VtG    = (bf16*)(ws + 132120576);   // aliases Tmp: live ranges disjoint
  int*  gate   = (int*)(ws + 165675008);

  hipMemcpyAsync(cur, x, (size_t)8388608 * 4, hipMemcpyDeviceToDevice, stream);

  f2b_kernel<<<3072, 256, 0, stream>>>(in_w, wb_in, 3145728);
  f2b_kernel<<<1024, 256, 0, stream>>>(o_w, wb_out, 1048576);
  f2b_kernel<<<4096, 256, 0, stream>>>(w1, wb_f1, 4194304);
  f2b_kernel<<<4096, 256, 0, stream>>>(w2, wb_f2, 4194304);
  split3_kernel<<<1024, 256, 0, stream>>>(rw1, r1h, r1m, r1l, 1048576);

  // ---- router: 6-pass split-bf16 GEMM for fp32-accurate logits ----
  ln_kernel<3><<<8192, 256, 0, stream>>>(x, r_nw, r_nb, Abuf, Bbuf, Big);
  dim3 g1k(8, 64);
  gemm_nt<5><<<g1k, 256, 0, stream>>>(Abuf, r1h, nullptr, nullptr, Tmp, nullptr, nullptr, 8192, 1024, 1024, 0);
  gemm_nt<4><<<g1k, 256, 0, stream>>>(Abuf, r1m, nullptr, nullptr, Tmp, nullptr, nullptr, 8192, 1024, 1024, 0);
  gemm_nt<4><<<g1k, 256, 0, stream>>>(Bbuf, r1h, nullptr, nullptr, Tmp, nullptr, nullptr, 8192, 1024, 1024, 0);
  gemm_nt<4><<<g1k, 256, 0, stream>>>(Abuf, r1l, nullptr, nullptr, Tmp, nullptr, nullptr, 8192, 1024, 1024, 0);
  gemm_nt<4><<<g1k, 256, 0, stream>>>(Bbuf, r1m, nullptr, nullptr, Tmp, nullptr, nullptr, 8192, 1024, 1024, 0);
  gemm_nt<4><<<g1k, 256, 0, stream>>>(Big,  r1h, nullptr, nullptr, Tmp, nullptr, nullptr, 8192, 1024, 1024, 0);
  gelu_bias_kernel<<<8192, 256, 0, stream>>>(Tmp, rb1, 8388608);
  router_logits<<<2048, 256, 0, stream>>>(Tmp, rw2, rb2, logits, depths, gate);

  // ---- 6 recursion levels ----
  for (int level = 1; level <= 6; level++) {
    ln_kernel<1><<<8192, 256, 0, stream>>>(cur, a_nw, a_nb, Abuf, nullptr, nullptr);
    gemm_nt<0><<<dim3(24, 64), 256, 0, stream>>>(Abuf, wb_in, in_b, nullptr, nullptr, Big, nullptr, 8192, 3072, 1024, 0);
    vtrans_kernel<<<2048, 256, 0, stream>>>(Big, VtG);
    attn_kernel<<<2048, 256, 0, stream>>>(Big, VtG, Bbuf);
    gemm_nt<1><<<dim3(8, 64), 256, 0, stream>>>(Bbuf, wb_out, o_b, cur, Tmp, nullptr, nullptr, 8192, 1024, 1024, 0);
    ln_kernel<1><<<8192, 256, 0, stream>>>(Tmp, f_nw, f_nb, Abuf, nullptr, nullptr);
    gemm_nt<2><<<dim3(32, 64), 256, 0, stream>>>(Abuf, wb_f1, b1, nullptr, nullptr, Big, nullptr, 8192, 4096, 1024, 0);
    gemm_nt<3><<<dim3(8, 64), 256, 0, stream>>>(Big, wb_f2, b2, Tmp, cur, nullptr, gate, 8192, 1024, 4096, level);
  }
}

// Round 3
// 2819.882 us; speedup vs baseline: 1.2754x; 1.0696x over previous
//
#include <hip/hip_runtime.h>
#include <cstdint>
#include <cstddef>

typedef __bf16 bf16;
typedef bf16 bf16x8 __attribute__((ext_vector_type(8)));
typedef float f32x4 __attribute__((ext_vector_type(4)));

#define GAS __attribute__((address_space(1)))
#define LAS __attribute__((address_space(3)))

__device__ __forceinline__ void async_cp16(const bf16* g, bf16* l) {
  __builtin_amdgcn_global_load_lds((const GAS unsigned int*)g,
                                   (LAS unsigned int*)l, 16, 0, 0);
}

__device__ __forceinline__ float gelu_f(float x) {
  return 0.5f * x * (1.0f + erff(x * 0.70710678118654752440f));
}

// ---------------- weight conversion ----------------
__global__ void __launch_bounds__(256) f2b_kernel(const float* __restrict__ in,
                                                  bf16* __restrict__ out, int n) {
  int i = (blockIdx.x * 256 + threadIdx.x) * 4;
  if (i >= n) return;
  float4 v = *(const float4*)&in[i];
  union { uint2 u; bf16 e[4]; } o;
  o.e[0] = (bf16)v.x; o.e[1] = (bf16)v.y; o.e[2] = (bf16)v.z; o.e[3] = (bf16)v.w;
  *(uint2*)&out[i] = o.u;
}

// 3-way hi/mid/lo split for the precision-critical router GEMM
__global__ void __launch_bounds__(256) split3_kernel(const float* __restrict__ in,
    bf16* __restrict__ oh, bf16* __restrict__ om, bf16* __restrict__ ol, int n) {
  int i = (blockIdx.x * 256 + threadIdx.x) * 4;
  if (i >= n) return;
  float4 v = *(const float4*)&in[i];
  float a[4] = {v.x, v.y, v.z, v.w};
  union { uint2 u; bf16 e[4]; } h, m, l;
#pragma unroll
  for (int j = 0; j < 4; j++) {
    h.e[j] = (bf16)a[j];
    float r = a[j] - (float)h.e[j];
    m.e[j] = (bf16)r;
    l.e[j] = (bf16)(r - (float)m.e[j]);
  }
  *(uint2*)&oh[i] = h.u;
  *(uint2*)&om[i] = m.u;
  *(uint2*)&ol[i] = l.u;
}

// ---------------- layernorm (fp32 in, bf16 out; optional 3-way split) ----------------
template<int SPLIT>
__global__ void __launch_bounds__(256) ln_kernel(const float* __restrict__ X,
    const float* __restrict__ w, const float* __restrict__ b,
    bf16* __restrict__ oh, bf16* __restrict__ om, bf16* __restrict__ ol) {
  const int row = blockIdx.x;
  const int tid = threadIdx.x;
  const float4 xv = *(const float4*)&X[(size_t)row * 1024 + tid * 4];
  float s1 = xv.x + xv.y + xv.z + xv.w;
  float s2 = xv.x * xv.x + xv.y * xv.y + xv.z * xv.z + xv.w * xv.w;
#pragma unroll
  for (int d = 1; d < 64; d <<= 1) {
    s1 += __shfl_xor(s1, d, 64);
    s2 += __shfl_xor(s2, d, 64);
  }
  __shared__ float red[8];
  if ((tid & 63) == 0) { red[tid >> 6] = s1; red[4 + (tid >> 6)] = s2; }
  __syncthreads();
  s1 = red[0] + red[1] + red[2] + red[3];
  s2 = red[4] + red[5] + red[6] + red[7];
  const float mu = s1 * (1.0f / 1024.0f);
  const float var = s2 * (1.0f / 1024.0f) - mu * mu;
  const float rs = rsqrtf(var + 1e-5f);
  const float4 wv = *(const float4*)&w[tid * 4];
  const float4 bv = *(const float4*)&b[tid * 4];
  float y[4] = {(xv.x - mu) * rs * wv.x + bv.x,
                (xv.y - mu) * rs * wv.y + bv.y,
                (xv.z - mu) * rs * wv.z + bv.z,
                (xv.w - mu) * rs * wv.w + bv.w};
  union { uint2 u; bf16 e[4]; } h;
#pragma unroll
  for (int j = 0; j < 4; j++) h.e[j] = (bf16)y[j];
  *(uint2*)&oh[(size_t)row * 1024 + tid * 4] = h.u;
  if (SPLIT == 3) {
    union { uint2 u; bf16 e[4]; } m, l;
#pragma unroll
    for (int j = 0; j < 4; j++) {
      float r = y[j] - (float)h.e[j];
      m.e[j] = (bf16)r;
      l.e[j] = (bf16)(r - (float)m.e[j]);
    }
    *(uint2*)&om[(size_t)row * 1024 + tid * 4] = m.u;
    *(uint2*)&ol[(size_t)row * 1024 + tid * 4] = l.u;
  }
}

// XCD-aware block remap: XCD = id%8 owns an m-slice (mb % 8 == XCD) and sweeps
// n fastest -> each A-tile is HBM-fetched by exactly one XCD, re-read from L2.
__device__ __forceinline__ void swizzle_mn(int gx, int& m0, int& n0) {
  const int id = blockIdx.y * gx + blockIdx.x;
  const int k8 = id & 7, t = id >> 3;
  n0 = (t % gx) * 128;
  m0 = ((t / gx) * 8 + k8) * 128;
}

// ---------------- m97-style NT GEMM: C[M,N] = A[M,K] * B[N,K]^T ----------------
template<int MODE>
__global__ void __launch_bounds__(256) gemm_nt(
    const bf16* __restrict__ A, const bf16* __restrict__ B,
    const float* __restrict__ bias, const float* __restrict__ Res,
    float* __restrict__ C32, bf16* __restrict__ Cb,
    const int* __restrict__ gate, int M, int N, int K, int level) {
  __shared__ bf16 As[128 * 32];
  __shared__ bf16 Bs[128 * 32];
  const int tid = threadIdx.x;
  const int w = tid >> 6, lane = tid & 63;
  const int lr = lane & 15, lq = lane >> 4;
  int m0, n0;
  swizzle_mn(gridDim.x, m0, n0);
  const int wm = (w >> 1) * 64, wn = (w & 1) * 64;

  f32x4 acc[4][4] = {};

  const bf16* ga = A + (size_t)(m0 + (tid >> 2)) * K + (tid & 3) * 8;
  const bf16* gb = B + (size_t)(n0 + (tid >> 2)) * K + (tid & 3) * 8;
  bf16* la = As + w * 512;
  bf16* lb = Bs + w * 512;
  const size_t step64 = (size_t)64 * K;

  for (int k0 = 0; k0 < K; k0 += 32) {
    __syncthreads();
    async_cp16(ga + k0, la);
    async_cp16(ga + step64 + k0, la + 2048);
    async_cp16(gb + k0, lb);
    async_cp16(gb + step64 + k0, lb + 2048);
    __syncthreads();
    bf16x8 af[4], bfr[4];
#pragma unroll
    for (int i = 0; i < 4; i++)
      af[i] = *(const bf16x8*)&As[(wm + i * 16 + lr) * 32 + lq * 8];
#pragma unroll
    for (int i = 0; i < 4; i++)
      bfr[i] = *(const bf16x8*)&Bs[(wn + i * 16 + lr) * 32 + lq * 8];
#pragma unroll
    for (int mi = 0; mi < 4; mi++)
#pragma unroll
      for (int ni = 0; ni < 4; ni++)
        acc[mi][ni] = __builtin_amdgcn_mfma_f32_16x16x32_bf16(
            af[mi], bfr[ni], acc[mi][ni], 0, 0, 0);
  }

#pragma unroll
  for (int mi = 0; mi < 4; mi++) {
    const int rbase = m0 + wm + mi * 16 + lq * 4;
#pragma unroll
    for (int ni = 0; ni < 4; ni++) {
      const int c = n0 + wn + ni * 16 + lr;
      float bv = 0.0f;
      if (MODE <= 3) bv = bias[c];
#pragma unroll
      for (int r = 0; r < 4; r++) {
        const size_t row = (size_t)(rbase + r);
        const float v = acc[mi][ni][r];
        if (MODE == 0) {
          Cb[row * N + c] = (bf16)(v + bv);
        } else if (MODE == 1) {
          C32[row * N + c] = Res[row * N + c] + v + bv;
        } else if (MODE == 2) {
          Cb[row * N + c] = (bf16)gelu_f(v + bv);
        } else if (MODE == 3) {
          if (gate[row] >= level) C32[row * N + c] = Res[row * N + c] + v + bv;
        } else if (MODE == 4) {
          C32[row * N + c] += v;
        } else {
          C32[row * N + c] = v;
        }
      }
    }
  }
}

// ---------------- fused 6-product split-bf16 router GEMM ----------------
// C = Ah*Bh' + Ah*Bm' + Am*Bh' + Am*Bm' + Ah*Bl' + Al*Bh'   (M=8192,N=1024,K=1024)
__global__ void __launch_bounds__(256) gemm_router(
    const bf16* __restrict__ Ah, const bf16* __restrict__ Am, const bf16* __restrict__ Al,
    const bf16* __restrict__ Bh, const bf16* __restrict__ Bm, const bf16* __restrict__ Bl,
    float* __restrict__ C32) {
  __shared__ bf16 As[3][128 * 32];
  __shared__ bf16 Bs[3][128 * 32];
  const int tid = threadIdx.x;
  const int w = tid >> 6, lane = tid & 63;
  const int lr = lane & 15, lq = lane >> 4;
  int m0, n0;
  swizzle_mn(gridDim.x, m0, n0);
  const int wm = (w >> 1) * 64, wn = (w & 1) * 64;
  const int K = 1024;

  f32x4 acc[4][4] = {};

  const size_t aoff = (size_t)(m0 + (tid >> 2)) * K + (tid & 3) * 8;
  const size_t boff = (size_t)(n0 + (tid >> 2)) * K + (tid & 3) * 8;
  const bf16* gA[3] = {Ah + aoff, Am + aoff, Al + aoff};
  const bf16* gB[3] = {Bh + boff, Bm + boff, Bl + boff};
  const int lo = w * 512;
  const size_t step64 = (size_t)64 * K;

  const int cA[6] = {0, 0, 1, 1, 0, 2};
  const int cB[6] = {0, 1, 0, 1, 2, 0};

  for (int k0 = 0; k0 < K; k0 += 32) {
    __syncthreads();
#pragma unroll
    for (int j = 0; j < 3; j++) {
      async_cp16(gA[j] + k0, As[j] + lo);
      async_cp16(gA[j] + step64 + k0, As[j] + lo + 2048);
      async_cp16(gB[j] + k0, Bs[j] + lo);
      async_cp16(gB[j] + step64 + k0, Bs[j] + lo + 2048);
    }
    __syncthreads();
#pragma unroll
    for (int c = 0; c < 6; c++) {
      bf16x8 af[4], bfr[4];
#pragma unroll
      for (int i = 0; i < 4; i++)
        af[i] = *(const bf16x8*)&As[cA[c]][(wm + i * 16 + lr) * 32 + lq * 8];
#pragma unroll
      for (int i = 0; i < 4; i++)
        bfr[i] = *(const bf16x8*)&Bs[cB[c]][(wn + i * 16 + lr) * 32 + lq * 8];
#pragma unroll
      for (int mi = 0; mi < 4; mi++)
#pragma unroll
        for (int ni = 0; ni < 4; ni++)
          acc[mi][ni] = __builtin_amdgcn_mfma_f32_16x16x32_bf16(
              af[mi], bfr[ni], acc[mi][ni], 0, 0, 0);
    }
  }

#pragma unroll
  for (int mi = 0; mi < 4; mi++) {
    const int rbase = m0 + wm + mi * 16 + lq * 4;
#pragma unroll
    for (int ni = 0; ni < 4; ni++) {
      const int c = n0 + wn + ni * 16 + lr;
#pragma unroll
      for (int r = 0; r < 4; r++)
        C32[(size_t)(rbase + r) * 1024 + c] = acc[mi][ni][r];
    }
  }
}

// ---------------- router tail ----------------
__global__ void __launch_bounds__(256) gelu_bias_kernel(float* __restrict__ t,
    const float* __restrict__ bias, int n) {
  int i = (blockIdx.x * 256 + threadIdx.x) * 4;
  if (i >= n) return;
  float4 v = *(const float4*)&t[i];
  float4 bb = *(const float4*)&bias[i & 1023];
  v.x = gelu_f(v.x + bb.x);
  v.y = gelu_f(v.y + bb.y);
  v.z = gelu_f(v.z + bb.z);
  v.w = gelu_f(v.w + bb.w);
  *(float4*)&t[i] = v;
}

__global__ void __launch_bounds__(256) router_logits(const float* __restrict__ h,
    const float* __restrict__ w2, const float* __restrict__ b2,
    float* __restrict__ logits_out, float* __restrict__ depths_out,
    int* __restrict__ gate) {
  const int row = blockIdx.x * 4 + (threadIdx.x >> 6);
  const int lane = threadIdx.x & 63;
  const float* hr = h + (size_t)row * 1024;
  float part[6] = {0, 0, 0, 0, 0, 0};
  for (int kc = lane; kc < 256; kc += 64) {
    float4 hv = *(const float4*)&hr[kc * 4];
#pragma unroll
    for (int j = 0; j < 6; j++) {
      float4 wv = *(const float4*)&w2[j * 1024 + kc * 4];
      part[j] += hv.x * wv.x + hv.y * wv.y + hv.z * wv.z + hv.w * wv.w;
    }
  }
#pragma unroll
  for (int j = 0; j < 6; j++)
#pragma unroll
    for (int d = 1; d < 64; d <<= 1) part[j] += __shfl_xor(part[j], d, 64);
  if (lane == 0) {
    float best = -1e30f;
    int bi = 0;
#pragma unroll
    for (int j = 0; j < 6; j++) {
      const float v = part[j] + b2[j];
      logits_out[(size_t)row * 6 + j] = v;
      if (v > best) { best = v; bi = j; }
    }
    depths_out[row] = (float)(bi + 1);
    gate[row] = bi + 1;
  }
}

// ---------------- V transpose: qkv V-slice -> vt (b,h,hd,tok) ----------------
__global__ void __launch_bounds__(256) vtrans_kernel(const bf16* __restrict__ qkv,
                                                     bf16* __restrict__ vt) {
  __shared__ bf16 T[64 * 64];
  const int tid = threadIdx.x;
  const int tb = blockIdx.x & 15, bh = blockIdx.x >> 4;
  const int b = bh >> 4, h = bh & 15;
#pragma unroll
  for (int i = 0; i < 2; i++) {
    const int c = tid + i * 256;
    const int tok = c >> 3, hd8 = (c & 7) * 8;
    uint4 v = *(const uint4*)&qkv[((size_t)b * 1024 + tb * 64 + tok) * 3072 + 2048 + h * 64 + hd8];
    *(uint4*)&T[tok * 64 + (hd8 ^ ((tok & 7) << 3))] = v;
  }
  __syncthreads();
#pragma unroll
  for (int i = 0; i < 2; i++) {
    const int c = tid + i * 256;
    const int hd = c >> 3, t8 = (c & 7) * 8;
    union { uint4 u; bf16 e[8]; } o;
#pragma unroll
    for (int j = 0; j < 8; j++)
      o.e[j] = T[(t8 + j) * 64 + (hd ^ (j << 3))];
    *(uint4*)&vt[((size_t)bh * 64 + hd) * 1024 + tb * 64 + t8] = o.u;
  }
}

// ---------------- flash attention (no-max softmax, deferred reductions) ----------------
__global__ void __launch_bounds__(256) attn_kernel(const bf16* __restrict__ qkv,
                                                   const bf16* __restrict__ vtg,
                                                   bf16* __restrict__ ctx) {
  __shared__ bf16 Qs[64 * 72];
  __shared__ bf16 Ks[64 * 72];
  __shared__ bf16 Vt[64 * 72];
  __shared__ bf16 Ps[64 * 72];
  const int tid = threadIdx.x;
  const int w = tid >> 6, lane = tid & 63;
  const int lr = lane & 15, lq = lane >> 4;
  const int blk = blockIdx.x;
  const int bh = (blk & 7) | ((blk >> 7) << 3);
  const int qt = (blk >> 3) & 15;
  const int b = bh >> 4, h = bh & 15;
  const size_t rowbase = (size_t)b * 1024;
  const int hcol = h * 64;
  const size_t vbase = (size_t)bh * 65536;

#pragma unroll
  for (int i = 0; i < 2; i++) {
    const int c = tid + i * 256;
    const int r = c >> 3, k8 = (c & 7) * 8;
    uint4 v = *(const uint4*)&qkv[(rowbase + qt * 64 + r) * 3072 + hcol + k8];
    *(uint4*)&Qs[r * 72 + k8] = v;
  }
  __syncthreads();
  bf16x8 aq[2];
#pragma unroll
  for (int hs = 0; hs < 2; hs++)
    aq[hs] = *(const bf16x8*)&Qs[(w * 16 + lr) * 72 + hs * 32 + lq * 8];

  float lsum[4] = {0.0f, 0.0f, 0.0f, 0.0f};
  f32x4 o[4];
#pragma unroll
  for (int i = 0; i < 4; i++) o[i] = (f32x4)0.0f;

  const int Sw = ((w * 4 + lq) & 7) << 3;
  const int Sr = ((w * 4 + (lr >> 2)) & 7) << 3;

  for (int kb = 0; kb < 16; kb++) {
    __syncthreads();
#pragma unroll
    for (int i = 0; i < 2; i++) {
      const int c = tid + i * 256;
      const int r = c >> 3, k8 = (c & 7) * 8;
      uint4 v = *(const uint4*)&qkv[(rowbase + kb * 64 + r) * 3072 + 1024 + hcol + k8];
      *(uint4*)&Ks[r * 72 + k8] = v;
    }
#pragma unroll
    for (int i = 0; i < 2; i++) {
      const int c = tid + i * 256;
      const int hd = c >> 3, t8 = (c & 7) * 8;
      uint4 v = *(const uint4*)&vtg[vbase + (size_t)hd * 1024 + kb * 64 + t8];
      *(uint4*)&Vt[hd * 72 + (t8 ^ (hd & 56))] = v;
    }
    __syncthreads();

    f32x4 s[4];
#pragma unroll
    for (int kf = 0; kf < 4; kf++) {
      f32x4 sa = (f32x4)0.0f;
#pragma unroll
      for (int hs = 0; hs < 2; hs++) {
        bf16x8 bk = *(const bf16x8*)&Ks[(kf * 16 + lr) * 72 + hs * 32 + lq * 8];
        sa = __builtin_amdgcn_mfma_f32_16x16x32_bf16(aq[hs], bk, sa, 0, 0, 0);
      }
      s[kf] = sa;
    }

#pragma unroll
    for (int kf = 0; kf < 4; kf++) {
#pragma unroll
      for (int r = 0; r < 4; r++) {
        const float p = __expf(s[kf][r] * 0.125f);
        lsum[r] += p;
        const int row = w * 16 + lq * 4 + r;
        Ps[row * 72 + ((kf * 16 + lr) ^ Sw)] = (bf16)p;
      }
    }

    bf16x8 ap[2];
#pragma unroll
    for (int ks = 0; ks < 2; ks++)
      ap[ks] = *(const bf16x8*)&Ps[(w * 16 + lr) * 72 + ((ks * 32 + lq * 8) ^ Sr)];
#pragma unroll
    for (int hf = 0; hf < 4; hf++) {
      const int vrow = hf * 16 + lr;
#pragma unroll
      for (int ks = 0; ks < 2; ks++) {
        bf16x8 bv = *(const bf16x8*)&Vt[vrow * 72 + ((ks * 32 + lq * 8) ^ (vrow & 56))];
        o[hf] = __builtin_amdgcn_mfma_f32_16x16x32_bf16(ap[ks], bv, o[hf], 0, 0, 0);
      }
    }
  }

#pragma unroll
  for (int r = 0; r < 4; r++) {
#pragma unroll
    for (int d = 1; d < 16; d <<= 1) lsum[r] += __shfl_xor(lsum[r], d, 64);
  }

#pragma unroll
  for (int r = 0; r < 4; r++) {
    const float inv = 1.0f / lsum[r];
    const size_t row = rowbase + qt * 64 + w * 16 + lq * 4 + r;
#pragma unroll
    for (int hf = 0; hf < 4; hf++)
      ctx[row * 1024 + hcol + hf * 16 + lr] = (bf16)(o[hf][r] * inv);
  }
}

// ---------------- launch ----------------
extern "C" void kernel_launch(void* const* d_in, const int* in_sizes, int n_in,
                              void* d_out, int out_size, void* d_ws, size_t ws_size,
                              hipStream_t stream) {
  (void)in_sizes; (void)n_in; (void)out_size; (void)ws_size;
  const float* x    = (const float*)d_in[0];
  const float* a_nw = (const float*)d_in[1];
  const float* a_nb = (const float*)d_in[2];
  const float* in_w = (const float*)d_in[3];
  const float* in_b = (const float*)d_in[4];
  const float* o_w  = (const float*)d_in[5];
  const float* o_b  = (const float*)d_in[6];
  const float* f_nw = (const float*)d_in[7];
  const float* f_nb = (const float*)d_in[8];
  const float* w1   = (const float*)d_in[9];
  const float* b1   = (const float*)d_in[10];
  const float* w2   = (const float*)d_in[11];
  const float* b2   = (const float*)d_in[12];
  const float* r_nw = (const float*)d_in[13];
  const float* r_nb = (const float*)d_in[14];
  const float* rw1  = (const float*)d_in[15];
  const float* rb1  = (const float*)d_in[16];
  const float* rw2  = (const float*)d_in[17];
  const float* rb2  = (const float*)d_in[18];

  float* cur    = (float*)d_out;
  float* depths = cur + 8388608;
  float* logits = depths + 8192;

  char* ws = (char*)d_ws;
  bf16* wb_in  = (bf16*)(ws + 0);
  bf16* wb_out = (bf16*)(ws + 6291456);
  bf16* wb_f1  = (bf16*)(ws + 8388608);
  bf16* wb_f2  = (bf16*)(ws + 16777216);
  bf16* r1h    = (bf16*)(ws + 25165824);
  bf16* r1m    = (bf16*)(ws + 27262976);
  bf16* r1l    = (bf16*)(ws + 29360128);
  bf16* Abuf   = (bf16*)(ws + 31457280);
  bf16* Bbuf   = (bf16*)(ws + 48234496);
  bf16* Big    = (bf16*)(ws + 65011712);
  float* Tmp   = (float*)(ws + 132120576);
  bf16* VtG    = (bf16*)(ws + 132120576);   // aliases Tmp: live ranges disjoint
  int*  gate   = (int*)(ws + 165675008);

  hipMemcpyAsync(cur, x, (size_t)8388608 * 4, hipMemcpyDeviceToDevice, stream);

  f2b_kernel<<<3072, 256, 0, stream>>>(in_w, wb_in, 3145728);
  f2b_kernel<<<1024, 256, 0, stream>>>(o_w, wb_out, 1048576);
  f2b_kernel<<<4096, 256, 0, stream>>>(w1, wb_f1, 4194304);
  f2b_kernel<<<4096, 256, 0, stream>>>(w2, wb_f2, 4194304);
  split3_kernel<<<1024, 256, 0, stream>>>(rw1, r1h, r1m, r1l, 1048576);

  // ---- router: fused 6-product split-bf16 GEMM for fp32-accurate logits ----
  ln_kernel<3><<<8192, 256, 0, stream>>>(x, r_nw, r_nb, Abuf, Bbuf, Big);
  gemm_router<<<dim3(8, 64), 256, 0, stream>>>(Abuf, Bbuf, Big, r1h, r1m, r1l, Tmp);
  gelu_bias_kernel<<<8192, 256, 0, stream>>>(Tmp, rb1, 8388608);
  router_logits<<<2048, 256, 0, stream>>>(Tmp, rw2, rb2, logits, depths, gate);

  // ---- 6 recursion levels ----
  for (int level = 1; level <= 6; level++) {
    ln_kernel<1><<<8192, 256, 0, stream>>>(cur, a_nw, a_nb, Abuf, nullptr, nullptr);
    gemm_nt<0><<<dim3(24, 64), 256, 0, stream>>>(Abuf, wb_in, in_b, nullptr, nullptr, Big, nullptr, 8192, 3072, 1024, 0);
    vtrans_kernel<<<2048, 256, 0, stream>>>(Big, VtG);
    attn_kernel<<<2048, 256, 0, stream>>>(Big, VtG, Bbuf);
    gemm_nt<1><<<dim3(8, 64), 256, 0, stream>>>(Bbuf, wb_out, o_b, cur, Tmp, nullptr, nullptr, 8192, 1024, 1024, 0);
    ln_kernel<1><<<8192, 256, 0, stream>>>(Tmp, f_nw, f_nb, Abuf, nullptr, nullptr);
    gemm_nt<2><<<dim3(32, 64), 256, 0, stream>>>(Abuf, wb_f1, b1, nullptr, nullptr, Big, nullptr, 8192, 4096, 1024, 0);
    gemm_nt<3><<<dim3(8, 64), 256, 0, stream>>>(Big, wb_f2, b2, Tmp, cur, nullptr, gate, 8192, 1024, 4096, level);
  }
}

// Round 4
// 2586.168 us; speedup vs baseline: 1.3906x; 1.0904x over previous
//
#include <hip/hip_runtime.h>
#include <cstdint>
#include <cstddef>

typedef __bf16 bf16;
typedef bf16 bf16x8 __attribute__((ext_vector_type(8)));
typedef float f32x4 __attribute__((ext_vector_type(4)));

#define GAS __attribute__((address_space(1)))
#define LAS __attribute__((address_space(3)))

__device__ __forceinline__ void async_cp16(const bf16* g, bf16* l) {
  __builtin_amdgcn_global_load_lds((const GAS unsigned int*)g,
                                   (LAS unsigned int*)l, 16, 0, 0);
}

__device__ __forceinline__ float gelu_f(float x) {
  return 0.5f * x * (1.0f + erff(x * 0.70710678118654752440f));
}

// ---------------- weight conversion ----------------
__global__ void __launch_bounds__(256) f2b_kernel(const float* __restrict__ in,
                                                  bf16* __restrict__ out, int n) {
  int i = (blockIdx.x * 256 + threadIdx.x) * 4;
  if (i >= n) return;
  float4 v = *(const float4*)&in[i];
  union { uint2 u; bf16 e[4]; } o;
  o.e[0] = (bf16)v.x; o.e[1] = (bf16)v.y; o.e[2] = (bf16)v.z; o.e[3] = (bf16)v.w;
  *(uint2*)&out[i] = o.u;
}

__global__ void __launch_bounds__(256) split3_kernel(const float* __restrict__ in,
    bf16* __restrict__ oh, bf16* __restrict__ om, bf16* __restrict__ ol, int n) {
  int i = (blockIdx.x * 256 + threadIdx.x) * 4;
  if (i >= n) return;
  float4 v = *(const float4*)&in[i];
  float a[4] = {v.x, v.y, v.z, v.w};
  union { uint2 u; bf16 e[4]; } h, m, l;
#pragma unroll
  for (int j = 0; j < 4; j++) {
    h.e[j] = (bf16)a[j];
    float r = a[j] - (float)h.e[j];
    m.e[j] = (bf16)r;
    l.e[j] = (bf16)(r - (float)m.e[j]);
  }
  *(uint2*)&oh[i] = h.u;
  *(uint2*)&om[i] = m.u;
  *(uint2*)&ol[i] = l.u;
}

// ---------------- layernorm (full M; optional 3-way split) ----------------
template<int SPLIT>
__global__ void __launch_bounds__(256) ln_kernel(const float* __restrict__ X,
    const float* __restrict__ w, const float* __restrict__ b,
    bf16* __restrict__ oh, bf16* __restrict__ om, bf16* __restrict__ ol) {
  const int row = blockIdx.x;
  const int tid = threadIdx.x;
  const float4 xv = *(const float4*)&X[(size_t)row * 1024 + tid * 4];
  float s1 = xv.x + xv.y + xv.z + xv.w;
  float s2 = xv.x * xv.x + xv.y * xv.y + xv.z * xv.z + xv.w * xv.w;
#pragma unroll
  for (int d = 1; d < 64; d <<= 1) {
    s1 += __shfl_xor(s1, d, 64);
    s2 += __shfl_xor(s2, d, 64);
  }
  __shared__ float red[8];
  if ((tid & 63) == 0) { red[tid >> 6] = s1; red[4 + (tid >> 6)] = s2; }
  __syncthreads();
  s1 = red[0] + red[1] + red[2] + red[3];
  s2 = red[4] + red[5] + red[6] + red[7];
  const float mu = s1 * (1.0f / 1024.0f);
  const float var = s2 * (1.0f / 1024.0f) - mu * mu;
  const float rs = rsqrtf(var + 1e-5f);
  const float4 wv = *(const float4*)&w[tid * 4];
  const float4 bv = *(const float4*)&b[tid * 4];
  float y[4] = {(xv.x - mu) * rs * wv.x + bv.x,
                (xv.y - mu) * rs * wv.y + bv.y,
                (xv.z - mu) * rs * wv.z + bv.z,
                (xv.w - mu) * rs * wv.w + bv.w};
  union { uint2 u; bf16 e[4]; } h;
#pragma unroll
  for (int j = 0; j < 4; j++) h.e[j] = (bf16)y[j];
  *(uint2*)&oh[(size_t)row * 1024 + tid * 4] = h.u;
  if (SPLIT == 3) {
    union { uint2 u; bf16 e[4]; } m, l;
#pragma unroll
    for (int j = 0; j < 4; j++) {
      float r = y[j] - (float)h.e[j];
      m.e[j] = (bf16)r;
      l.e[j] = (bf16)(r - (float)m.e[j]);
    }
    *(uint2*)&om[(size_t)row * 1024 + tid * 4] = m.u;
    *(uint2*)&ol[(size_t)row * 1024 + tid * 4] = l.u;
  }
}

// ---------------- layernorm on compacted rows, zero-fill to 128-pad ----------------
__global__ void __launch_bounds__(256) ln_c_kernel(const float* __restrict__ X,
    const float* __restrict__ w, const float* __restrict__ b,
    bf16* __restrict__ oh, const int* __restrict__ cnt_ptr) {
  const int row = blockIdx.x;
  const int cnt = *cnt_ptr;
  const int pad = (cnt + 127) & ~127;
  if (row >= pad) return;
  const int tid = threadIdx.x;
  if (row >= cnt) {
    *(uint2*)&oh[(size_t)row * 1024 + tid * 4] = make_uint2(0, 0);
    return;
  }
  const float4 xv = *(const float4*)&X[(size_t)row * 1024 + tid * 4];
  float s1 = xv.x + xv.y + xv.z + xv.w;
  float s2 = xv.x * xv.x + xv.y * xv.y + xv.z * xv.z + xv.w * xv.w;
#pragma unroll
  for (int d = 1; d < 64; d <<= 1) {
    s1 += __shfl_xor(s1, d, 64);
    s2 += __shfl_xor(s2, d, 64);
  }
  __shared__ float red[8];
  if ((tid & 63) == 0) { red[tid >> 6] = s1; red[4 + (tid >> 6)] = s2; }
  __syncthreads();
  s1 = red[0] + red[1] + red[2] + red[3];
  s2 = red[4] + red[5] + red[6] + red[7];
  const float mu = s1 * (1.0f / 1024.0f);
  const float var = s2 * (1.0f / 1024.0f) - mu * mu;
  const float rs = rsqrtf(var + 1e-5f);
  const float4 wv = *(const float4*)&w[tid * 4];
  const float4 bv = *(const float4*)&b[tid * 4];
  union { uint2 u; bf16 e[4]; } h;
  h.e[0] = (bf16)((xv.x - mu) * rs * wv.x + bv.x);
  h.e[1] = (bf16)((xv.y - mu) * rs * wv.y + bv.y);
  h.e[2] = (bf16)((xv.z - mu) * rs * wv.z + bv.z);
  h.e[3] = (bf16)((xv.w - mu) * rs * wv.w + bv.w);
  *(uint2*)&oh[(size_t)row * 1024 + tid * 4] = h.u;
}

// ---------------- depth-compaction index build ----------------
__global__ void zero_cnt_kernel(int* cnt_all, int* bcnt_all) {
  if (threadIdx.x < 6) cnt_all[threadIdx.x] = 0;
  if (threadIdx.x < 48) bcnt_all[threadIdx.x] = 0;
}

__global__ void __launch_bounds__(256) build_idx_kernel(
    const int* __restrict__ gate, int* __restrict__ idx_all,
    int* __restrict__ cnt_all, int* __restrict__ bidx_all,
    int* __restrict__ bcnt_all) {
  const int lev = blockIdx.x >> 3;   // 0..5
  const int b   = blockIdx.x & 7;
  const int level = lev + 1;
  int* idx  = idx_all + lev * 8192;
  int* bidx = bidx_all + lev * 8192 + b * 1024;
  for (int t = threadIdx.x; t < 1024; t += 256) {
    const int row = b * 1024 + t;
    if (gate[row] >= level) {
      int p = atomicAdd(&bcnt_all[lev * 8 + b], 1);
      bidx[p] = t;
      int q = atomicAdd(&cnt_all[lev], 1);
      idx[q] = row;
    }
  }
}

// XCD-aware block remap: XCD = id%8 owns an m-slice, sweeps n fastest.
__device__ __forceinline__ void swizzle_mn(int gx, int& m0, int& n0) {
  const int id = blockIdx.y * gx + blockIdx.x;
  const int k8 = id & 7, t = id >> 3;
  n0 = (t % gx) * 128;
  m0 = ((t / gx) * 8 + k8) * 128;
}

// ---------------- NT GEMM with compaction modes ----------------
// MODE 0: qkv_kv  A full;                Cb[i*ldc+coff+c] = bf16(acc+bias)
// MODE 1: qkv_q   A gather idx;          Cb[idx[i]*ldc+c] = bf16(acc+bias)   (guard)
// MODE 2: outproj A gather idx; Res gather; C32[i*N+c] = Res[idx[i]]+acc+bias (compact out)
// MODE 3: ffn-up  A compact;             Cb[i*N+c] = bf16(gelu(acc+bias))
// MODE 4: ffn-dn  A compact; Res compact; C32[idx[i]*N+c] = Res[i]+acc+bias  (guard)
template<int MODE>
__global__ void __launch_bounds__(256) gemm_nt(
    const bf16* __restrict__ A, const bf16* __restrict__ B,
    const float* __restrict__ bias, const float* __restrict__ Res,
    float* __restrict__ C32, bf16* __restrict__ Cb,
    const int* __restrict__ idx, const int* __restrict__ cnt_ptr,
    int N, int K, int ldc, int coff) {
  __shared__ bf16 As[128 * 32];
  __shared__ bf16 Bs[128 * 32];
  const int tid = threadIdx.x;
  const int w = tid >> 6, lane = tid & 63;
  const int lr = lane & 15, lq = lane >> 4;
  int m0, n0;
  swizzle_mn(gridDim.x, m0, n0);
  int cnt = 0x7fffffff;
  if (MODE != 0) {
    cnt = *cnt_ptr;
    if (m0 >= cnt) return;
  }
  const int wm = (w >> 1) * 64, wn = (w & 1) * 64;

  f32x4 acc[4][4] = {};

  const int i0 = m0 + (tid >> 2), i1 = i0 + 64;
  size_t ar0, ar1;
  if (MODE == 1 || MODE == 2) {
    ar0 = (size_t)idx[i0 < cnt ? i0 : 0];
    ar1 = (size_t)idx[i1 < cnt ? i1 : 0];
  } else {
    ar0 = (size_t)i0; ar1 = (size_t)i1;
  }
  const bf16* ga0 = A + ar0 * K + (tid & 3) * 8;
  const bf16* ga1 = A + ar1 * K + (tid & 3) * 8;
  const bf16* gb = B + (size_t)(n0 + (tid >> 2)) * K + (tid & 3) * 8;
  bf16* la = As + w * 512;
  bf16* lb = Bs + w * 512;
  const size_t bstep = (size_t)64 * K;

  for (int k0 = 0; k0 < K; k0 += 32) {
    __syncthreads();
    async_cp16(ga0 + k0, la);
    async_cp16(ga1 + k0, la + 2048);
    async_cp16(gb + k0, lb);
    async_cp16(gb + bstep + k0, lb + 2048);
    __syncthreads();
    bf16x8 af[4], bfr[4];
#pragma unroll
    for (int i = 0; i < 4; i++)
      af[i] = *(const bf16x8*)&As[(wm + i * 16 + lr) * 32 + lq * 8];
#pragma unroll
    for (int i = 0; i < 4; i++)
      bfr[i] = *(const bf16x8*)&Bs[(wn + i * 16 + lr) * 32 + lq * 8];
#pragma unroll
    for (int mi = 0; mi < 4; mi++)
#pragma unroll
      for (int ni = 0; ni < 4; ni++)
        acc[mi][ni] = __builtin_amdgcn_mfma_f32_16x16x32_bf16(
            af[mi], bfr[ni], acc[mi][ni], 0, 0, 0);
  }

#pragma unroll
  for (int mi = 0; mi < 4; mi++) {
    const int rbase = m0 + wm + mi * 16 + lq * 4;
    int orig[4];
#pragma unroll
    for (int r = 0; r < 4; r++) {
      const int i = rbase + r;
      if (MODE == 1 || MODE == 2 || MODE == 4) orig[r] = (i < cnt) ? idx[i] : -1;
      else orig[r] = i;
    }
#pragma unroll
    for (int ni = 0; ni < 4; ni++) {
      const int c = n0 + wn + ni * 16 + lr;
      const float bv = bias[c];
#pragma unroll
      for (int r = 0; r < 4; r++) {
        const float v = acc[mi][ni][r] + bv;
        const int i = rbase + r;
        if (MODE == 0) {
          Cb[(size_t)i * ldc + coff + c] = (bf16)v;
        } else if (MODE == 1) {
          if (orig[r] >= 0) Cb[(size_t)orig[r] * ldc + c] = (bf16)v;
        } else if (MODE == 2) {
          const float rv = (orig[r] >= 0) ? Res[(size_t)orig[r] * N + c] : 0.0f;
          C32[(size_t)i * N + c] = rv + v;
        } else if (MODE == 3) {
          Cb[(size_t)i * N + c] = (bf16)gelu_f(v);
        } else {
          if (orig[r] >= 0)
            C32[(size_t)orig[r] * N + c] = Res[(size_t)i * N + c] + v;
        }
      }
    }
  }
}

// ---------------- fused 6-product split-bf16 router GEMM ----------------
__global__ void __launch_bounds__(256) gemm_router(
    const bf16* __restrict__ Ah, const bf16* __restrict__ Am, const bf16* __restrict__ Al,
    const bf16* __restrict__ Bh, const bf16* __restrict__ Bm, const bf16* __restrict__ Bl,
    float* __restrict__ C32) {
  __shared__ bf16 As[3][128 * 32];
  __shared__ bf16 Bs[3][128 * 32];
  const int tid = threadIdx.x;
  const int w = tid >> 6, lane = tid & 63;
  const int lr = lane & 15, lq = lane >> 4;
  int m0, n0;
  swizzle_mn(gridDim.x, m0, n0);
  const int wm = (w >> 1) * 64, wn = (w & 1) * 64;
  const int K = 1024;

  f32x4 acc[4][4] = {};

  const size_t aoff = (size_t)(m0 + (tid >> 2)) * K + (tid & 3) * 8;
  const size_t boff = (size_t)(n0 + (tid >> 2)) * K + (tid & 3) * 8;
  const bf16* gA[3] = {Ah + aoff, Am + aoff, Al + aoff};
  const bf16* gB[3] = {Bh + boff, Bm + boff, Bl + boff};
  const int lo = w * 512;
  const size_t step64 = (size_t)64 * K;

  const int cA[6] = {0, 0, 1, 1, 0, 2};
  const int cB[6] = {0, 1, 0, 1, 2, 0};

  for (int k0 = 0; k0 < K; k0 += 32) {
    __syncthreads();
#pragma unroll
    for (int j = 0; j < 3; j++) {
      async_cp16(gA[j] + k0, As[j] + lo);
      async_cp16(gA[j] + step64 + k0, As[j] + lo + 2048);
      async_cp16(gB[j] + k0, Bs[j] + lo);
      async_cp16(gB[j] + step64 + k0, Bs[j] + lo + 2048);
    }
    __syncthreads();
#pragma unroll
    for (int c = 0; c < 6; c++) {
      bf16x8 af[4], bfr[4];
#pragma unroll
      for (int i = 0; i < 4; i++)
        af[i] = *(const bf16x8*)&As[cA[c]][(wm + i * 16 + lr) * 32 + lq * 8];
#pragma unroll
      for (int i = 0; i < 4; i++)
        bfr[i] = *(const bf16x8*)&Bs[cB[c]][(wn + i * 16 + lr) * 32 + lq * 8];
#pragma unroll
      for (int mi = 0; mi < 4; mi++)
#pragma unroll
        for (int ni = 0; ni < 4; ni++)
          acc[mi][ni] = __builtin_amdgcn_mfma_f32_16x16x32_bf16(
              af[mi], bfr[ni], acc[mi][ni], 0, 0, 0);
    }
  }

#pragma unroll
  for (int mi = 0; mi < 4; mi++) {
    const int rbase = m0 + wm + mi * 16 + lq * 4;
#pragma unroll
    for (int ni = 0; ni < 4; ni++) {
      const int c = n0 + wn + ni * 16 + lr;
#pragma unroll
      for (int r = 0; r < 4; r++)
        C32[(size_t)(rbase + r) * 1024 + c] = acc[mi][ni][r];
    }
  }
}

// ---------------- router tail ----------------
__global__ void __launch_bounds__(256) gelu_bias_kernel(float* __restrict__ t,
    const float* __restrict__ bias, int n) {
  int i = (blockIdx.x * 256 + threadIdx.x) * 4;
  if (i >= n) return;
  float4 v = *(const float4*)&t[i];
  float4 bb = *(const float4*)&bias[i & 1023];
  v.x = gelu_f(v.x + bb.x);
  v.y = gelu_f(v.y + bb.y);
  v.z = gelu_f(v.z + bb.z);
  v.w = gelu_f(v.w + bb.w);
  *(float4*)&t[i] = v;
}

__global__ void __launch_bounds__(256) router_logits(const float* __restrict__ h,
    const float* __restrict__ w2, const float* __restrict__ b2,
    float* __restrict__ logits_out, float* __restrict__ depths_out,
    int* __restrict__ gate) {
  const int row = blockIdx.x * 4 + (threadIdx.x >> 6);
  const int lane = threadIdx.x & 63;
  const float* hr = h + (size_t)row * 1024;
  float part[6] = {0, 0, 0, 0, 0, 0};
  for (int kc = lane; kc < 256; kc += 64) {
    float4 hv = *(const float4*)&hr[kc * 4];
#pragma unroll
    for (int j = 0; j < 6; j++) {
      float4 wv = *(const float4*)&w2[j * 1024 + kc * 4];
      part[j] += hv.x * wv.x + hv.y * wv.y + hv.z * wv.z + hv.w * wv.w;
    }
  }
#pragma unroll
  for (int j = 0; j < 6; j++)
#pragma unroll
    for (int d = 1; d < 64; d <<= 1) part[j] += __shfl_xor(part[j], d, 64);
  if (lane == 0) {
    float best = -1e30f;
    int bi = 0;
#pragma unroll
    for (int j = 0; j < 6; j++) {
      const float v = part[j] + b2[j];
      logits_out[(size_t)row * 6 + j] = v;
      if (v > best) { best = v; bi = j; }
    }
    depths_out[row] = (float)(bi + 1);
    gate[row] = bi + 1;
  }
}

// ---------------- V transpose ----------------
__global__ void __launch_bounds__(256) vtrans_kernel(const bf16* __restrict__ qkv,
                                                     bf16* __restrict__ vt) {
  __shared__ bf16 T[64 * 64];
  const int tid = threadIdx.x;
  const int tb = blockIdx.x & 15, bh = blockIdx.x >> 4;
  const int b = bh >> 4, h = bh & 15;
#pragma unroll
  for (int i = 0; i < 2; i++) {
    const int c = tid + i * 256;
    const int tok = c >> 3, hd8 = (c & 7) * 8;
    uint4 v = *(const uint4*)&qkv[((size_t)b * 1024 + tb * 64 + tok) * 3072 + 2048 + h * 64 + hd8];
    *(uint4*)&T[tok * 64 + (hd8 ^ ((tok & 7) << 3))] = v;
  }
  __syncthreads();
#pragma unroll
  for (int i = 0; i < 2; i++) {
    const int c = tid + i * 256;
    const int hd = c >> 3, t8 = (c & 7) * 8;
    union { uint4 u; bf16 e[8]; } o;
#pragma unroll
    for (int j = 0; j < 8; j++)
      o.e[j] = T[(t8 + j) * 64 + (hd ^ (j << 3))];
    *(uint4*)&vt[((size_t)bh * 64 + hd) * 1024 + tb * 64 + t8] = o.u;
  }
}

// ---------------- flash attention, compacted q-rows ----------------
__global__ void __launch_bounds__(256) attn_kernel(const bf16* __restrict__ qkv,
    const bf16* __restrict__ vtg, bf16* __restrict__ ctx,
    const int* __restrict__ bidx, const int* __restrict__ bcnt) {
  __shared__ bf16 Qs[64 * 72];
  __shared__ bf16 Ks[64 * 72];
  __shared__ bf16 Vt[64 * 72];
  __shared__ bf16 Ps[64 * 72];
  __shared__ int Ts[64];
  const int tid = threadIdx.x;
  const int w = tid >> 6, lane = tid & 63;
  const int lr = lane & 15, lq = lane >> 4;
  const int blk = blockIdx.x;
  const int bh = (blk & 7) | ((blk >> 7) << 3);
  const int qt = (blk >> 3) & 15;
  const int b = bh >> 4, h = bh & 15;
  const int nb = bcnt[b];
  if (qt * 64 >= nb) return;
  const size_t rowbase = (size_t)b * 1024;
  const int hcol = h * 64;
  const size_t vbase = (size_t)bh * 65536;

  if (tid < 64) {
    const int j = qt * 64 + tid;
    Ts[tid] = (j < nb) ? bidx[b * 1024 + j] : bidx[b * 1024 + qt * 64];
  }
  __syncthreads();

#pragma unroll
  for (int i = 0; i < 2; i++) {
    const int c = tid + i * 256;
    const int r = c >> 3, k8 = (c & 7) * 8;
    uint4 v = *(const uint4*)&qkv[(rowbase + Ts[r]) * 3072 + hcol + k8];
    *(uint4*)&Qs[r * 72 + k8] = v;
  }
  __syncthreads();
  bf16x8 aq[2];
#pragma unroll
  for (int hs = 0; hs < 2; hs++)
    aq[hs] = *(const bf16x8*)&Qs[(w * 16 + lr) * 72 + hs * 32 + lq * 8];

  float lsum[4] = {0.0f, 0.0f, 0.0f, 0.0f};
  f32x4 o[4];
#pragma unroll
  for (int i = 0; i < 4; i++) o[i] = (f32x4)0.0f;

  const int Sw = ((w * 4 + lq) & 7) << 3;
  const int Sr = ((w * 4 + (lr >> 2)) & 7) << 3;

  for (int kb = 0; kb < 16; kb++) {
    __syncthreads();
#pragma unroll
    for (int i = 0; i < 2; i++) {
      const int c = tid + i * 256;
      const int r = c >> 3, k8 = (c & 7) * 8;
      uint4 v = *(const uint4*)&qkv[(rowbase + kb * 64 + r) * 3072 + 1024 + hcol + k8];
      *(uint4*)&Ks[r * 72 + k8] = v;
    }
#pragma unroll
    for (int i = 0; i < 2; i++) {
      const int c = tid + i * 256;
      const int hd = c >> 3, t8 = (c & 7) * 8;
      uint4 v = *(const uint4*)&vtg[vbase + (size_t)hd * 1024 + kb * 64 + t8];
      *(uint4*)&Vt[hd * 72 + (t8 ^ (hd & 56))] = v;
    }
    __syncthreads();

    f32x4 s[4];
#pragma unroll
    for (int kf = 0; kf < 4; kf++) {
      f32x4 sa = (f32x4)0.0f;
#pragma unroll
      for (int hs = 0; hs < 2; hs++) {
        bf16x8 bk = *(const bf16x8*)&Ks[(kf * 16 + lr) * 72 + hs * 32 + lq * 8];
        sa = __builtin_amdgcn_mfma_f32_16x16x32_bf16(aq[hs], bk, sa, 0, 0, 0);
      }
      s[kf] = sa;
    }

#pragma unroll
    for (int kf = 0; kf < 4; kf++) {
#pragma unroll
      for (int r = 0; r < 4; r++) {
        const float p = __expf(s[kf][r] * 0.125f);
        lsum[r] += p;
        const int row = w * 16 + lq * 4 + r;
        Ps[row * 72 + ((kf * 16 + lr) ^ Sw)] = (bf16)p;
      }
    }

    bf16x8 ap[2];
#pragma unroll
    for (int ks = 0; ks < 2; ks++)
      ap[ks] = *(const bf16x8*)&Ps[(w * 16 + lr) * 72 + ((ks * 32 + lq * 8) ^ Sr)];
#pragma unroll
    for (int hf = 0; hf < 4; hf++) {
      const int vrow = hf * 16 + lr;
#pragma unroll
      for (int ks = 0; ks < 2; ks++) {
        bf16x8 bv = *(const bf16x8*)&Vt[vrow * 72 + ((ks * 32 + lq * 8) ^ (vrow & 56))];
        o[hf] = __builtin_amdgcn_mfma_f32_16x16x32_bf16(ap[ks], bv, o[hf], 0, 0, 0);
      }
    }
  }

#pragma unroll
  for (int r = 0; r < 4; r++) {
#pragma unroll
    for (int d = 1; d < 16; d <<= 1) lsum[r] += __shfl_xor(lsum[r], d, 64);
  }

#pragma unroll
  for (int r = 0; r < 4; r++) {
    const int rowj = w * 16 + lq * 4 + r;
    if (qt * 64 + rowj < nb) {
      const float inv = 1.0f / lsum[r];
      const size_t row = rowbase + Ts[rowj];
#pragma unroll
      for (int hf = 0; hf < 4; hf++)
        ctx[row * 1024 + hcol + hf * 16 + lr] = (bf16)(o[hf][r] * inv);
    }
  }
}

// ---------------- launch ----------------
extern "C" void kernel_launch(void* const* d_in, const int* in_sizes, int n_in,
                              void* d_out, int out_size, void* d_ws, size_t ws_size,
                              hipStream_t stream) {
  (void)in_sizes; (void)n_in; (void)out_size; (void)ws_size;
  const float* x    = (const float*)d_in[0];
  const float* a_nw = (const float*)d_in[1];
  const float* a_nb = (const float*)d_in[2];
  const float* in_w = (const float*)d_in[3];
  const float* in_b = (const float*)d_in[4];
  const float* o_w  = (const float*)d_in[5];
  const float* o_b  = (const float*)d_in[6];
  const float* f_nw = (const float*)d_in[7];
  const float* f_nb = (const float*)d_in[8];
  const float* w1   = (const float*)d_in[9];
  const float* b1   = (const float*)d_in[10];
  const float* w2   = (const float*)d_in[11];
  const float* b2   = (const float*)d_in[12];
  const float* r_nw = (const float*)d_in[13];
  const float* r_nb = (const float*)d_in[14];
  const float* rw1  = (const float*)d_in[15];
  const float* rb1  = (const float*)d_in[16];
  const float* rw2  = (const float*)d_in[17];
  const float* rb2  = (const float*)d_in[18];

  float* cur    = (float*)d_out;
  float* depths = cur + 8388608;
  float* logits = depths + 8192;

  char* ws = (char*)d_ws;
  bf16* wb_in  = (bf16*)(ws + 0);
  bf16* wb_out = (bf16*)(ws + 6291456);
  bf16* wb_f1  = (bf16*)(ws + 8388608);
  bf16* wb_f2  = (bf16*)(ws + 16777216);
  bf16* r1h    = (bf16*)(ws + 25165824);
  bf16* r1m    = (bf16*)(ws + 27262976);
  bf16* r1l    = (bf16*)(ws + 29360128);
  bf16* Abuf   = (bf16*)(ws + 31457280);
  bf16* Bbuf   = (bf16*)(ws + 48234496);
  bf16* Big    = (bf16*)(ws + 65011712);
  float* Tmp   = (float*)(ws + 132120576);
  bf16* VtG    = (bf16*)(ws + 132120576);   // aliases Tmp: live ranges disjoint
  int*  gate   = (int*)(ws + 165675008);
  // idx/cnt arrays alias the router split-weight buffers (dead after gemm_router)
  int* idx_all  = (int*)(ws + 25165824);    // 6*8192 ints (aliases r1h)
  int* bidx_all = (int*)(ws + 27262976);    // 6*8192 ints (aliases r1m)
  int* cnt_all  = (int*)(ws + 29360128);    // 6 ints      (aliases r1l)
  int* bcnt_all = cnt_all + 16;             // 48 ints

  hipMemcpyAsync(cur, x, (size_t)8388608 * 4, hipMemcpyDeviceToDevice, stream);

  f2b_kernel<<<3072, 256, 0, stream>>>(in_w, wb_in, 3145728);
  f2b_kernel<<<1024, 256, 0, stream>>>(o_w, wb_out, 1048576);
  f2b_kernel<<<4096, 256, 0, stream>>>(w1, wb_f1, 4194304);
  f2b_kernel<<<4096, 256, 0, stream>>>(w2, wb_f2, 4194304);
  split3_kernel<<<1024, 256, 0, stream>>>(rw1, r1h, r1m, r1l, 1048576);

  // ---- router ----
  ln_kernel<3><<<8192, 256, 0, stream>>>(x, r_nw, r_nb, Abuf, Bbuf, Big);
  gemm_router<<<dim3(8, 64), 256, 0, stream>>>(Abuf, Bbuf, Big, r1h, r1m, r1l, Tmp);
  gelu_bias_kernel<<<8192, 256, 0, stream>>>(Tmp, rb1, 8388608);
  router_logits<<<2048, 256, 0, stream>>>(Tmp, rw2, rb2, logits, depths, gate);
  zero_cnt_kernel<<<1, 64, 0, stream>>>(cnt_all, bcnt_all);
  build_idx_kernel<<<48, 256, 0, stream>>>(gate, idx_all, cnt_all, bidx_all, bcnt_all);

  // ---- 6 recursion levels, depth-compacted ----
  for (int level = 1; level <= 6; level++) {
    const int lev = level - 1;
    const int* idxL  = idx_all + lev * 8192;
    const int* cntL  = cnt_all + lev;
    const int* bidxL = bidx_all + lev * 8192;
    const int* bcntL = bcnt_all + lev * 8;

    ln_kernel<1><<<8192, 256, 0, stream>>>(cur, a_nw, a_nb, Abuf, nullptr, nullptr);
    // K,V projection: all rows (frozen tokens still serve as keys/values)
    gemm_nt<0><<<dim3(16, 64), 256, 0, stream>>>(Abuf, wb_in + 1048576, in_b + 1024,
        nullptr, nullptr, Big, nullptr, nullptr, 2048, 1024, 3072, 1024);
    // Q projection: active rows only, scatter into Big
    gemm_nt<1><<<dim3(8, 64), 256, 0, stream>>>(Abuf, wb_in, in_b,
        nullptr, nullptr, Big, idxL, cntL, 1024, 1024, 3072, 0);
    vtrans_kernel<<<2048, 256, 0, stream>>>(Big, VtG);
    attn_kernel<<<2048, 256, 0, stream>>>(Big, VtG, Bbuf, bidxL, bcntL);
    // out-proj: gather ctx + residual, compact output
    gemm_nt<2><<<dim3(8, 64), 256, 0, stream>>>(Bbuf, wb_out, o_b,
        cur, Tmp, nullptr, idxL, cntL, 1024, 1024, 0, 0);
    ln_c_kernel<<<8192, 256, 0, stream>>>(Tmp, f_nw, f_nb, Abuf, cntL);
    gemm_nt<3><<<dim3(32, 64), 256, 0, stream>>>(Abuf, wb_f1, b1,
        nullptr, nullptr, Big, idxL, cntL, 4096, 1024, 0, 0);
    gemm_nt<4><<<dim3(8, 64), 256, 0, stream>>>(Big, wb_f2, b2,
        Tmp, cur, nullptr, idxL, cntL, 1024, 4096, 0, 0);
  }
}